// Round 6
// baseline (655.397 us; speedup 1.0000x reference)
//
#include <hip/hip_runtime.h>

// Problem constants: B=2, S=2048 -> T=4096 tokens; D=1024, H=4096, E=8, top-2.
#define T_TOK 4096
#define DIM   1024
#define HID   4096
#define NEXP  8
#define MAXROWS 9216

typedef unsigned short u16;
typedef __attribute__((ext_vector_type(8))) short short8;   // 8 bf16 (4 VGPRs) MFMA frag
typedef __attribute__((ext_vector_type(4))) float f32x4;
typedef __attribute__((ext_vector_type(4))) unsigned short u16x4;
typedef __attribute__((ext_vector_type(8))) unsigned short u16x8;

typedef __attribute__((address_space(3))) unsigned int lds_uint;
typedef __attribute__((address_space(3))) u16 lds_u16;
typedef const __attribute__((address_space(1))) unsigned int gbl_uint;

__device__ __forceinline__ u16 f2bf(float f) {
    union { float f; unsigned int u; } v; v.f = f;
    unsigned int r = v.u + 0x7fffu + ((v.u >> 16) & 1u);   // RNE
    return (u16)(r >> 16);
}

// fast gelu (tanh form): max |err| vs exact erf-gelu ~3e-4, well under budget
__device__ __forceinline__ float gelu_f(float v) {
    float u = 1.5957691216f * (v + 0.044715f * v * v * v);   // 2*0.7978845608*(...)
    float s = 1.0f / (1.0f + __expf(-u));                    // sigmoid(2u') == 0.5*(1+tanh(u'))
    return v * s;
}

// asm ds_read_b128: invisible to compiler memory model -> no auto vmcnt(0) drain
// before LDS reads of global_load_lds-written data (rule 18 / m201 pattern).
// MUST be followed by s_waitcnt lgkmcnt(0) + sched_barrier(0) before consuming.
__device__ __forceinline__ short8 ds_read128(unsigned byte_addr) {
    short8 r;
    asm volatile("ds_read_b128 %0, %1" : "=v"(r) : "v"(byte_addr));
    return r;
}

// ---------------- blocked transpose+cast for BOTH weights; also zeroes counts.
// fp32 [K][N] per expert -> bf16 BLOCKED tiles: [e][ct][kt][128n x 64k].
__global__ __launch_bounds__(256)
void transpose_blocked(const float* __restrict__ w1, u16* __restrict__ w1t,
                       const float* __restrict__ w2, u16* __restrict__ w2t,
                       int* __restrict__ counts) {
    int b = blockIdx.x;
    if (b == 0 && threadIdx.x < NEXP) counts[threadIdx.x] = 0;
    const float* in; u16* out; int C, KT, ct, kt, e;
    if (b < 4096) {
        e = b >> 9; int t = b & 511; ct = t & 31; kt = t >> 5;   // CT=32, KT=16
        in = w1; out = w1t; C = HID; KT = 16;
    } else {
        b -= 4096;
        e = b >> 9; int t = b & 511; ct = t & 7; kt = t >> 3;    // CT=8, KT=64
        in = w2; out = w2t; C = DIM; KT = 64;
    }
    __shared__ u16 tl[64 * 130];
    size_t mo = (size_t)e * DIM * HID;
    const float* ip = in + mo + (size_t)(kt * 64) * C + ct * 128;
    u16* op = out + mo + (size_t)(ct * KT + kt) * 8192;
    int tid = threadIdx.x;
#pragma unroll
    for (int j = 0; j < 8; ++j) {
        int id = tid + 256 * j;
        int kr = id >> 5, cg = id & 31;
        f32x4 v = *(const f32x4*)(ip + (size_t)kr * C + 4 * cg);
        u16x4 w; w.x = f2bf(v.x); w.y = f2bf(v.y); w.z = f2bf(v.z); w.w = f2bf(v.w);
        *(u16x4*)(tl + kr * 130 + 4 * cg) = w;
    }
    __syncthreads();
#pragma unroll
    for (int j = 0; j < 4; ++j) {
        int id = tid + 256 * j;
        int n = id >> 3, c = id & 7;
        u16x8 o;
#pragma unroll
        for (int m = 0; m < 8; ++m) o[m] = tl[(c * 8 + m) * 130 + n];
        *(u16x8*)(op + id * 8) = o;
    }
}

// ---------------- router: logits -> softmax -> top2 -> renormalized gates
__global__ __launch_bounds__(256)
void router_k(const float* __restrict__ x, const float* __restrict__ rw,
              int* __restrict__ counts, int* __restrict__ tE,
              int* __restrict__ tS, float* __restrict__ tG) {
    int wave = threadIdx.x >> 6, lane = threadIdx.x & 63;
    int t = blockIdx.x * 4 + wave;
    const float* xr = x + (size_t)t * DIM;
    float xv[16];
#pragma unroll
    for (int i = 0; i < 16; ++i) xv[i] = xr[lane + 64*i];
    float lg[NEXP];
#pragma unroll
    for (int e = 0; e < NEXP; ++e) {
        const float* wr_ = rw + e * DIM;
        float a = 0.f;
#pragma unroll
        for (int i = 0; i < 16; ++i) a += xv[i] * wr_[lane + 64*i];
        lg[e] = a;
    }
#pragma unroll
    for (int off = 32; off > 0; off >>= 1)
#pragma unroll
        for (int e = 0; e < NEXP; ++e) lg[e] += __shfl_xor(lg[e], off, 64);
    if (lane == 0) {
        float mx = lg[0];
        for (int e = 1; e < NEXP; ++e) mx = fmaxf(mx, lg[e]);
        float p[NEXP], s = 0.f;
        for (int e = 0; e < NEXP; ++e) { p[e] = expf(lg[e] - mx); s += p[e]; }
        float inv_s = 1.f / s;
        for (int e = 0; e < NEXP; ++e) p[e] *= inv_s;
        int i0 = 0;
        for (int e = 1; e < NEXP; ++e) if (p[e] > p[i0]) i0 = e;
        int i1 = (i0 == 0) ? 1 : 0;
        for (int e = 0; e < NEXP; ++e) if (e != i0 && p[e] > p[i1]) i1 = e;
        float v0 = p[i0], v1 = p[i1];
        float inv = 1.f / (v0 + v1 + 1e-9f);
        int s0 = atomicAdd(&counts[i0], 1);
        int s1 = atomicAdd(&counts[i1], 1);
        tE[2*t] = i0;  tE[2*t+1] = i1;
        tS[2*t] = s0;  tS[2*t+1] = s1;
        tG[2*t] = v0 * inv;  tG[2*t+1] = v1 * inv;
    }
}

// inline exclusive scan of 128-padded counts: returns base for expert e
__device__ __forceinline__ int pbase_of(const int* __restrict__ counts, int e) {
    int pb = 0;
#pragma unroll
    for (int i = 0; i < NEXP; ++i) {
        int pad = ((counts[i] + 127) >> 7) << 7;
        pb += (i < e) ? pad : 0;
    }
    return pb;
}

// ---------------- gather x rows (fp32) into packed bf16 rows per assignment
__global__ __launch_bounds__(256)
void gather_k(const float* __restrict__ x, const int* __restrict__ tE,
              const int* __restrict__ tS, const int* __restrict__ counts,
              u16* __restrict__ xg) {
    int a = blockIdx.x;              // 0..8191
    int t = a >> 1, k = a & 1;
    int e = tE[2*t + k];
    int row = pbase_of(counts, e) + tS[2*t + k];
    const f32x4* xr = (const f32x4*)(x + (size_t)t * DIM);
    u16x4* o = (u16x4*)(xg + (size_t)row * DIM);
    int i = threadIdx.x;
    f32x4 v = xr[i];
    u16x4 r; r.x = f2bf(v.x); r.y = f2bf(v.y); r.z = f2bf(v.z); r.w = f2bf(v.w);
    o[i] = r;
}

// ---------------- fc1 GEMM: 256x256 tile, BK=64, 8 waves (2Mx4N), dbuf LDS 128KB.
// m201-style counted-vmcnt pipeline with K-SPLIT HALF-TILES: per K-tile the 4
// staged units are A-klo/B-klo (k0-31) and A-khi/B-khi (k32-63). Phases P1/P2
// consume klo, P3/P4 consume khi. Each phase stages ONE half of tile t+1 in
// consumption order (A-klo,B-klo,A-khi,B-khi); waits are vmcnt(4) at P2 (khi(t)
// ready, klo(t+1) in flight) and vmcnt(4) at P4 (klo(t+1) ready, khi(t+1) in
// flight) -- never drains to 0 mid-loop, issue-to-wait distance ~3 phases.
// Per phase: asm ds_reads -> stage -> s_barrier -> lgkmcnt(0)+sched_barrier ->
// setprio(1) 16 MFMA setprio(0) -> [vmcnt] -> s_barrier. LDS swizzle: chunk
// gk = cs ^ ((r^(r>>2))&3): 2-way max on ds_read_b128 (free, m136).
template<int K, bool GELU, typename OutT>
__global__ __launch_bounds__(512, 2)
void gemm256(const u16* __restrict__ A, const u16* __restrict__ BtAll,
             OutT* __restrict__ C, const int* __restrict__ counts, int N) {
    constexpr int NT = K / 64;
    constexpr int KT = K / 64;           // blocked k-tiles per 128-col tile column
    int lin = blockIdx.x;
    int e = lin & 7, kk = lin >> 3;
    int ctb = kk & 15, mt = kk >> 4;
    int cnt = counts[e];
    if (mt * 256 >= cnt) return;
    int row0 = pbase_of(counts, e) + mt * 256;
    int limit = cnt - mt * 256;
    const u16* Bt = BtAll + (size_t)e * N * K;
    int col0 = ctb * 256;

    // per buf (32768 u16 = 64KB): A_klo 0, A_khi 8192, B_klo 16384, B_khi 24576
    __shared__ __align__(16) u16 smem[65536];

    int tid = threadIdx.x;
    int lane = tid & 63, w = tid >> 6;
    int quad = lane >> 4, m16 = lane & 15;
    int wr = (w >> 2) * 128, wc = (w & 3) * 64;

    // staging slots: tid and tid+512; r = slot>>2 (row/col 0..255), cs = slot&3;
    // global chunk gk = cs ^ f(r), f(r) = (r ^ (r>>2)) & 3
    const u16* gA[2]; const u16* gB[2]; int lds8[2];
#pragma unroll
    for (int l = 0; l < 2; ++l) {
        int slot = tid + l * 512;
        int r = slot >> 2, cs = slot & 3;
        int gk = cs ^ ((r ^ (r >> 2)) & 3);
        int ra = row0 + r; if (ra > MAXROWS - 1) ra = MAXROWS - 1;
        gA[l] = A + (size_t)ra * K + gk * 8;                       // + t*64 + s*32
        gB[l] = Bt + (size_t)((ctb * 2 + (r >> 7)) * KT) * 8192
                   + (r & 127) * 64 + gk * 8;                      // + t*8192 + s*32
        lds8[l] = slot * 8;                                        // u16 within region
    }
#define STG_A(l, t, s, buf) __builtin_amdgcn_global_load_lds( \
    (gbl_uint*)(gA[l] + (t) * 64 + (s) * 32), \
    (lds_uint*)(smem + (buf) * 32768 + (s) * 8192 + lds8[l]), 16, 0, 0)
#define STG_B(l, t, s, buf) __builtin_amdgcn_global_load_lds( \
    (gbl_uint*)(gB[l] + (t) * 8192 + (s) * 32), \
    (lds_uint*)(smem + (buf) * 32768 + 16384 + (s) * 8192 + lds8[l]), 16, 0, 0)

    // fragment byte addrs: row = wr + mi*16 + m16 (A), col = wc + ni*16 + m16 (B);
    // row&3 == m16&3 and (row>>2)&3 == (m16>>2)&3 -> f is thread-fixed
    int f3 = (m16 ^ (m16 >> 2)) & 3;
    unsigned smb = (unsigned)(size_t)(lds_u16*)smem;
    unsigned aF = smb + (unsigned)((wr + m16) * 64 + ((quad ^ f3) << 4));
    unsigned bF = smb + 32768u + (unsigned)((wc + m16) * 64 + ((quad ^ f3) << 4));
    // per-read offsets: + buf*65536 + s*16384 + (mi|ni)*1024 bytes

    f32x4 acc[8][4] = {};

    // prologue: stage tile 0 halves in consumption order; klo done, khi in flight
    STG_A(0, 0, 0, 0); STG_A(1, 0, 0, 0);
    STG_B(0, 0, 0, 0); STG_B(1, 0, 0, 0);
    STG_A(0, 0, 1, 0); STG_A(1, 0, 1, 0);
    STG_B(0, 0, 1, 0); STG_B(1, 0, 1, 0);
    asm volatile("s_waitcnt vmcnt(4)" ::: "memory");
    __builtin_amdgcn_s_barrier();

    short8 af[8], bf[2], bg[2];
    for (int t = 0; t < NT; ++t) {
        unsigned db = (t & 1) ? 65536u : 0u;
        int nb = (t + 1) & 1;
        bool st = (t + 1 < NT);
        // ---- P1: reads A s0 (8) + B n0-1 s0; stage A_klo(t+1); MFMA [mi][0..1]
#pragma unroll
        for (int mi = 0; mi < 8; ++mi) af[mi] = ds_read128(aF + db + mi * 1024);
        bf[0] = ds_read128(bF + db);
        bf[1] = ds_read128(bF + db + 1024);
        if (st) { STG_A(0, t + 1, 0, nb); STG_A(1, t + 1, 0, nb); }
        __builtin_amdgcn_s_barrier();
        asm volatile("s_waitcnt lgkmcnt(0)" ::: "memory");
        __builtin_amdgcn_sched_barrier(0);
        __builtin_amdgcn_s_setprio(1);
#pragma unroll
        for (int mi = 0; mi < 8; ++mi) {
            acc[mi][0] = __builtin_amdgcn_mfma_f32_16x16x32_bf16(af[mi], bf[0], acc[mi][0], 0, 0, 0);
            acc[mi][1] = __builtin_amdgcn_mfma_f32_16x16x32_bf16(af[mi], bf[1], acc[mi][1], 0, 0, 0);
        }
        __builtin_amdgcn_s_setprio(0);
        __builtin_amdgcn_s_barrier();
        // ---- P2: reads B n2-3 s0; stage B_klo(t+1); MFMA [mi][2..3]; vmcnt(4): khi(t) ready
        bg[0] = ds_read128(bF + db + 2048);
        bg[1] = ds_read128(bF + db + 3072);
        if (st) { STG_B(0, t + 1, 0, nb); STG_B(1, t + 1, 0, nb); }
        __builtin_amdgcn_s_barrier();
        asm volatile("s_waitcnt lgkmcnt(0)" ::: "memory");
        __builtin_amdgcn_sched_barrier(0);
        __builtin_amdgcn_s_setprio(1);
#pragma unroll
        for (int mi = 0; mi < 8; ++mi) {
            acc[mi][2] = __builtin_amdgcn_mfma_f32_16x16x32_bf16(af[mi], bg[0], acc[mi][2], 0, 0, 0);
            acc[mi][3] = __builtin_amdgcn_mfma_f32_16x16x32_bf16(af[mi], bg[1], acc[mi][3], 0, 0, 0);
        }
        __builtin_amdgcn_s_setprio(0);
        if (st) asm volatile("s_waitcnt vmcnt(4)" ::: "memory");
        else    asm volatile("s_waitcnt vmcnt(0)" ::: "memory");
        __builtin_amdgcn_s_barrier();
        // ---- P3: reads A s1 (8) + B n0-1 s1; stage A_khi(t+1); MFMA [mi][0..1]
#pragma unroll
        for (int mi = 0; mi < 8; ++mi) af[mi] = ds_read128(aF + db + 16384 + mi * 1024);
        bf[0] = ds_read128(bF + db + 16384);
        bf[1] = ds_read128(bF + db + 16384 + 1024);
        if (st) { STG_A(0, t + 1, 1, nb); STG_A(1, t + 1, 1, nb); }
        __builtin_amdgcn_s_barrier();
        asm volatile("s_waitcnt lgkmcnt(0)" ::: "memory");
        __builtin_amdgcn_sched_barrier(0);
        __builtin_amdgcn_s_setprio(1);
#pragma unroll
        for (int mi = 0; mi < 8; ++mi) {
            acc[mi][0] = __builtin_amdgcn_mfma_f32_16x16x32_bf16(af[mi], bf[0], acc[mi][0], 0, 0, 0);
            acc[mi][1] = __builtin_amdgcn_mfma_f32_16x16x32_bf16(af[mi], bf[1], acc[mi][1], 0, 0, 0);
        }
        __builtin_amdgcn_s_setprio(0);
        __builtin_amdgcn_s_barrier();
        // ---- P4: reads B n2-3 s1; stage B_khi(t+1); MFMA [mi][2..3]; vmcnt(4): klo(t+1) ready
        bg[0] = ds_read128(bF + db + 16384 + 2048);
        bg[1] = ds_read128(bF + db + 16384 + 3072);
        if (st) { STG_B(0, t + 1, 1, nb); STG_B(1, t + 1, 1, nb); }
        __builtin_amdgcn_s_barrier();
        asm volatile("s_waitcnt lgkmcnt(0)" ::: "memory");
        __builtin_amdgcn_sched_barrier(0);
        __builtin_amdgcn_s_setprio(1);
#pragma unroll
        for (int mi = 0; mi < 8; ++mi) {
            acc[mi][2] = __builtin_amdgcn_mfma_f32_16x16x32_bf16(af[mi], bg[0], acc[mi][2], 0, 0, 0);
            acc[mi][3] = __builtin_amdgcn_mfma_f32_16x16x32_bf16(af[mi], bg[1], acc[mi][3], 0, 0, 0);
        }
        __builtin_amdgcn_s_setprio(0);
        if (st) asm volatile("s_waitcnt vmcnt(4)" ::: "memory");
        __builtin_amdgcn_s_barrier();
    }
#undef STG_A
#undef STG_B

    // epilogue: C/D layout col=lane&15, row=quad*4+reg (verified r1-r3 structure)
    if (GELU) {
        __syncthreads();
#pragma unroll
        for (int mi = 0; mi < 8; ++mi) {
#pragma unroll
            for (int r = 0; r < 4; ++r) {
                int row = wr + mi * 16 + quad * 4 + r;
#pragma unroll
                for (int ni = 0; ni < 4; ++ni) {
                    int col = wc + ni * 16 + m16;
                    int ch = col >> 3, w8 = col & 7;
                    smem[row * 256 + (((ch ^ (row & 31)) << 3) | w8)] = f2bf(gelu_f(acc[mi][ni][r]));
                }
            }
        }
        __syncthreads();
        int rr = tid >> 5, ch = tid & 31;
#pragma unroll
        for (int it = 0; it < 16; ++it) {
            int row = it * 16 + rr;
            if (row < limit) {
                u16x8 v = *(const u16x8*)(smem + row * 256 + ((ch ^ (row & 31)) << 3));
                *(u16x8*)((u16*)C + (size_t)(row0 + row) * N + col0 + ch * 8) = v;
            }
        }
    } else {
#pragma unroll
        for (int mi = 0; mi < 8; ++mi)
#pragma unroll
            for (int r = 0; r < 4; ++r) {
                int rl = wr + mi * 16 + quad * 4 + r;
                if (rl < limit) {
                    float* rp = (float*)C + (size_t)(row0 + rl) * N + col0 + wc + m16;
#pragma unroll
                    for (int ni = 0; ni < 4; ++ni)
                        rp[ni * 16] = acc[mi][ni][r];
                }
            }
    }
}

// ---------------- fc2 GEMM (proven 128^2 m97 structure, blocked-B, no split-K)
template<int K, int KSPLIT, int NX, bool GELU, typename OutT>
__global__ __launch_bounds__(256)
void gemm_bt(const u16* __restrict__ A, const u16* __restrict__ BtAll,
             OutT* __restrict__ C, const int* __restrict__ counts,
             int N, size_t cstride) {
    int lin = blockIdx.x;
    int e = lin & 7;
    int kk = lin >> 3;
    int ct = kk % NX;
    int rest = kk / NX;
    int ks = rest % KSPLIT;
    int mt = rest / KSPLIT;
    int cnt = counts[e];
    if (mt * 128 >= cnt) return;
    int row0 = pbase_of(counts, e) + mt * 128;
    const u16* Bt = BtAll + (size_t)e * N * K;
    OutT* Cp = C + (size_t)ks * cstride;
    int col0 = ct * 128;
    const int kb0 = ks * (K / KSPLIT);
    constexpr int KT = K / 64;
    constexpr int KITER = K / KSPLIT / 64;

    __shared__ __align__(16) u16 smem[128 * 128];
    u16* As = smem;
    u16* Bs = smem + 128 * 64;

    int tid = threadIdx.x;
    int lane = tid & 63;
    int w = tid >> 6;
    int quad = lane >> 4, m16 = lane & 15;
    int wr = (w >> 1) * 64, wc = (w & 1) * 64;
    int rsub = lane >> 3;
    int kch  = lane & 7;
    int kchs = kch ^ rsub;

    const u16* ga[4];
    const u16* gb[4];
#pragma unroll
    for (int i = 0; i < 4; ++i) {
        int r = (w * 4 + i) * 8 + rsub;
        ga[i] = A  + (size_t)(row0 + r) * K + kb0 + kchs * 8;
        gb[i] = Bt + ((size_t)ct * KT + kb0 / 64) * 8192 + r * 64 + kchs * 8;
    }
    int sw = m16 & 7;
    const u16* aP0 = As + (wr + m16) * 64 + ((quad       ^ sw) << 3);
    const u16* aP1 = As + (wr + m16) * 64 + (((4 + quad) ^ sw) << 3);
    const u16* bP0 = Bs + (wc + m16) * 64 + ((quad       ^ sw) << 3);
    const u16* bP1 = Bs + (wc + m16) * 64 + (((4 + quad) ^ sw) << 3);

    f32x4 acc[4][4] = {};

    for (int kit = 0; kit < KITER; ++kit) {
#pragma unroll
        for (int i = 0; i < 4; ++i) {
            int grp = w * 4 + i;
            __builtin_amdgcn_global_load_lds((gbl_uint*)ga[i], (lds_uint*)(As + grp * 512), 16, 0, 0);
            __builtin_amdgcn_global_load_lds((gbl_uint*)gb[i], (lds_uint*)(Bs + grp * 512), 16, 0, 0);
            ga[i] += 64; gb[i] += 8192;
        }
        __syncthreads();
        {
            short8 af2[4], bfr[4];
#pragma unroll
            for (int mi = 0; mi < 4; ++mi) af2[mi] = *(const short8*)(aP0 + mi * 1024);
#pragma unroll
            for (int ni = 0; ni < 4; ++ni) bfr[ni] = *(const short8*)(bP0 + ni * 1024);
#pragma unroll
            for (int mi = 0; mi < 4; ++mi)
#pragma unroll
                for (int ni = 0; ni < 4; ++ni)
                    acc[mi][ni] = __builtin_amdgcn_mfma_f32_16x16x32_bf16(af2[mi], bfr[ni], acc[mi][ni], 0, 0, 0);
#pragma unroll
            for (int mi = 0; mi < 4; ++mi) af2[mi] = *(const short8*)(aP1 + mi * 1024);
#pragma unroll
            for (int ni = 0; ni < 4; ++ni) bfr[ni] = *(const short8*)(bP1 + ni * 1024);
#pragma unroll
            for (int mi = 0; mi < 4; ++mi)
#pragma unroll
                for (int ni = 0; ni < 4; ++ni)
                    acc[mi][ni] = __builtin_amdgcn_mfma_f32_16x16x32_bf16(af2[mi], bfr[ni], acc[mi][ni], 0, 0, 0);
        }
        __syncthreads();
    }

    if (GELU) {
#pragma unroll
        for (int mi = 0; mi < 4; ++mi) {
#pragma unroll
            for (int r = 0; r < 4; ++r) {
                int row = wr + mi * 16 + quad * 4 + r;
#pragma unroll
                for (int ni = 0; ni < 4; ++ni) {
                    int col = wc + ni * 16 + m16;
                    int c16 = col >> 3, w8 = col & 7;
                    smem[row * 128 + (((c16 ^ (row & 15)) << 3) | w8)] = f2bf(gelu_f(acc[mi][ni][r]));
                }
            }
        }
        __syncthreads();
        int row_b = tid >> 4, c16_b = tid & 15;
        const u16* ls = smem + row_b * 128 + (((c16_b ^ (row_b & 15)) << 3));
        u16* gp = (u16*)Cp + (size_t)(row0 + row_b) * N + col0 + c16_b * 8;
#pragma unroll
        for (int j = 0; j < 8; ++j) {
            *(u16x8*)gp = *(const u16x8*)ls;
            ls += 16 * 128;
            gp += (size_t)16 * N;
        }
    } else {
        float* gp = (float*)Cp + (size_t)(row0 + wr + quad * 4) * N + col0 + wc + m16;
#pragma unroll
        for (int mi = 0; mi < 4; ++mi)
#pragma unroll
            for (int r = 0; r < 4; ++r) {
                float* rp = gp + (size_t)(mi * 16 + r) * N;
#pragma unroll
                for (int ni = 0; ni < 4; ++ni)
                    rp[ni * 16] = acc[mi][ni][r];
            }
    }
}

// ---------------- combine: out[t] = g0*p[row0(t)] + g1*p[row1(t)]
__global__ __launch_bounds__(256)
void combine_k(const float* __restrict__ p0,
               const int* __restrict__ tE, const int* __restrict__ tS,
               const float* __restrict__ tG, const int* __restrict__ counts,
               float* __restrict__ out) {
    int t = blockIdx.x;
    int e0 = tE[2*t], e1 = tE[2*t+1];
    int r0 = pbase_of(counts, e0) + tS[2*t];
    int r1 = pbase_of(counts, e1) + tS[2*t+1];
    float g0 = tG[2*t], g1 = tG[2*t+1];
    int i = threadIdx.x;
    f32x4 a0 = ((const f32x4*)(p0 + (size_t)r0 * DIM))[i];
    f32x4 a1 = ((const f32x4*)(p0 + (size_t)r1 * DIM))[i];
    f32x4* o = (f32x4*)(out + (size_t)t * DIM);
    o[i] = g0 * a0 + g1 * a1;
}

extern "C" void kernel_launch(void* const* d_in, const int* in_sizes, int n_in,
                              void* d_out, int out_size, void* d_ws, size_t ws_size,
                              hipStream_t stream) {
    const float* x  = (const float*)d_in[0];   // [4096,1024]
    const float* rw = (const float*)d_in[1];   // [8,1024]
    const float* w1 = (const float*)d_in[2];   // [8,1024,4096]
    const float* w2 = (const float*)d_in[3];   // [8,4096,1024]
    float* out = (float*)d_out;

    char* ws = (char*)d_ws;
    u16* w1t = (u16*)(ws + 0);                 // bf16 blocked [E][512][8192]  67,108,864
    u16* xg  = (u16*)(ws + 67108864ull);       // bf16 [9216][D]               -> 85,983,232
    u16* w2t = (u16*)(ws + 85983232ull);       // bf16 blocked                 -> 153,092,096
    u16* hb  = (u16*)(ws + 153092096ull);      // bf16 [9216][H]               -> 228,589,568
    float* p0 = (float*)(ws + 0);              // fc2 out f32 [9216][D] aliases w1t (dead after fc1)
    int* ctrl   = (int*)(ws + 228589568ull);
    int* counts = ctrl;
    int* tE     = ctrl + 32;
    int* tS     = ctrl + 32 + 8192;
    float* tG   = (float*)(ctrl + 32 + 16384);

    transpose_blocked<<<8192, 256, 0, stream>>>(w1, w1t, w2, w2t, counts);
    router_k<<<T_TOK / 4, 256, 0, stream>>>(x, rw, counts, tE, tS, tG);
    gather_k<<<T_TOK * 2, 256, 0, stream>>>(x, tE, tS, counts, xg);
    // fc1 + gelu: 256^2 counted-vmcnt pipeline. 1D grid 8e x 16ctb x 5mt = 640.
    gemm256<DIM, true, u16><<<640, 512, 0, stream>>>(xg, w1t, hb, counts, HID);
    // fc2: proven 128^2, no split-K. 1D grid 8e x 8ct x 10mt = 640.
    gemm_bt<HID, 1, 8, false, float><<<640, 256, 0, stream>>>(
        hb, w2t, p0, counts, DIM, 0);
    combine_k<<<T_TOK, 256, 0, stream>>>(p0, tE, tS, tG, counts, out);
}